// Round 8
// baseline (279.094 us; speedup 1.0000x reference)
//
#include <hip/hip_runtime.h>

#define NN 100000
#define NE 1600000
#define PSHIFT 9
#define PSZ 512
#define NP ((NN + PSZ - 1) / PSZ)             // 196
#define BCHUNK 8192
#define NBIN ((NE + BCHUNK - 1) / BCHUNK)     // 196
#define SRCMASK 0x1FFFF                       // 17 bits (NN < 131072)
#define GMTILES ((NN + 63) / 64)              // 1563

typedef __attribute__((ext_vector_type(8))) short short8;
typedef __attribute__((ext_vector_type(4))) float f32x4;

__device__ __forceinline__ ushort f2bf(float f) {
    uint u = __float_as_uint(f);
    return (ushort)((u + 0x7FFFu + ((u >> 16) & 1u)) >> 16);   // RNE
}
__device__ __forceinline__ float bflo(uint u) { return __uint_as_float(u << 16); }
__device__ __forceinline__ float bfhi(uint u) { return __uint_as_float(u & 0xffff0000u); }
__device__ __forceinline__ uint packbf(float a, float b) {
    return (uint)f2bf(a) | ((uint)f2bf(b) << 16);
}

// ---------------------------------------------------------------------------
// CSR build, partition-local for write locality (round-4 proven).
// ---------------------------------------------------------------------------
__global__ __launch_bounds__(256) void k_phist(const int* __restrict__ dst,
                                               int* __restrict__ pcnt)
{
    __shared__ int cnt[256];
    const int tid = threadIdx.x;
    cnt[tid] = 0;
    __syncthreads();
    const long e0 = (long)blockIdx.x * BCHUNK;
    for (int i = tid; i < BCHUNK; i += 256) {
        long e = e0 + i;
        if (e < NE) atomicAdd(&cnt[dst[e] >> PSHIFT], 1);
    }
    __syncthreads();
    if (cnt[tid] > 0) atomicAdd(&pcnt[tid], cnt[tid]);
}

__global__ __launch_bounds__(256) void k_pscan(const int* __restrict__ pcnt,
                                               int* __restrict__ poff,
                                               int* __restrict__ gcur,
                                               int* __restrict__ rowptr)
{
    __shared__ int tmp[256];
    const int tid = threadIdx.x;
    int v = (tid < NP) ? pcnt[tid] : 0;
    tmp[tid] = v;
    __syncthreads();
    for (int off = 1; off < 256; off <<= 1) {
        int t = (tid >= off) ? tmp[tid - off] : 0;
        __syncthreads();
        tmp[tid] += t;
        __syncthreads();
    }
    int ex = tmp[tid] - v;
    if (tid < NP) { poff[tid] = ex; gcur[tid] = ex; }
    if (tid == 0) { poff[NP] = NE; rowptr[NN] = NE; }
}

__global__ __launch_bounds__(256) void k_binning(const int* __restrict__ src,
                                                 const int* __restrict__ dst,
                                                 int* __restrict__ gcur,
                                                 uint* __restrict__ packed)
{
    __shared__ int cnt[256];
    __shared__ int base[256];
    const int tid = threadIdx.x;
    const long e0 = (long)blockIdx.x * BCHUNK;
    cnt[tid] = 0;
    __syncthreads();
    for (int i = tid; i < BCHUNK; i += 256) {
        long e = e0 + i;
        if (e < NE) atomicAdd(&cnt[dst[e] >> PSHIFT], 1);
    }
    __syncthreads();
    if (cnt[tid] > 0) base[tid] = atomicAdd(&gcur[tid], cnt[tid]);
    cnt[tid] = 0;
    __syncthreads();
    for (int i = tid; i < BCHUNK; i += 256) {
        long e = e0 + i;
        if (e < NE) {
            int d = dst[e], s = src[e];
            int p = d >> PSHIFT;
            int ofs = atomicAdd(&cnt[p], 1);
            packed[base[p] + ofs] = (uint)s | ((uint)(d & (PSZ - 1)) << 17);
        }
    }
}

__global__ __launch_bounds__(256) void k_pfill(const uint* __restrict__ packed,
                                               const int* __restrict__ poff,
                                               int* __restrict__ rowptr,
                                               int* __restrict__ col)
{
    __shared__ int cnt[PSZ];
    __shared__ int cur[PSZ];
    __shared__ int tot[256];
    const int p   = blockIdx.x;
    const int tid = threadIdx.x;
    const int beg = poff[p], end = poff[p + 1];
    cnt[tid] = 0; cnt[tid + 256] = 0;
    __syncthreads();
    for (int i = beg + tid; i < end; i += 256)
        atomicAdd(&cnt[packed[i] >> 17], 1);
    __syncthreads();
    int v0 = cnt[tid * 2], v1 = cnt[tid * 2 + 1];
    int s  = v0 + v1;
    tot[tid] = s;
    __syncthreads();
    for (int off = 1; off < 256; off <<= 1) {
        int t = (tid >= off) ? tot[tid - off] : 0;
        __syncthreads();
        tot[tid] += t;
        __syncthreads();
    }
    int ex = tot[tid] - s + beg;
    cur[tid * 2]     = ex;
    cur[tid * 2 + 1] = ex + v0;
    int n0 = p * PSZ;
    if (n0 + tid * 2     < NN) rowptr[n0 + tid * 2]     = ex;
    if (n0 + tid * 2 + 1 < NN) rowptr[n0 + tid * 2 + 1] = ex + v0;
    __syncthreads();
    for (int i = beg + tid; i < end; i += 256) {
        uint v = packed[i];
        int pos = atomicAdd(&cur[v >> 17], 1);
        col[pos] = (int)(v & SRCMASK);
    }
}

// ---------------------------------------------------------------------------
// Weight prep: WbT1[256][128] = [W1_l | W1_r]^T bf16; WbT2[128][128]
// ---------------------------------------------------------------------------
__global__ __launch_bounds__(256) void k_castw(const float* __restrict__ W1l,
                                               const float* __restrict__ W1r,
                                               const float* __restrict__ W2l,
                                               const float* __restrict__ W2r,
                                               ushort* __restrict__ WbT1,
                                               ushort* __restrict__ WbT2)
{
    int i = blockIdx.x * 256 + threadIdx.x;
    if (i < 256 * 128) {
        int c = i >> 7, k = i & 127;
        float v = (c < 128) ? W1l[k * 128 + c] : W1r[k * 128 + (c - 128)];
        WbT1[i] = f2bf(v);
    } else if (i < 256 * 128 + 128 * 128) {
        int j = i - 256 * 128;
        int c = j >> 7, k = j & 127;
        float v = (c < 64) ? W2l[k * 64 + c] : W2r[k * 64 + (c - 64)];
        WbT2[j] = f2bf(v);
    }
}

// ---------------------------------------------------------------------------
// Fused dual-GEMM per layer: [z | y] = A @ [Wl | Wr] (+bias on y part).
// B panel (all NCOL cols x K=128) staged ONCE per block in swizzled LDS;
// block grid-strides over m-tiles (64 rows each), staging A per tile.
// 4 waves; wave w covers cols [w*16*CB, (w+1)*16*CB).
// ---------------------------------------------------------------------------
template <bool IS_L1>
__global__ __launch_bounds__(256) void k_gemmf(const void* __restrict__ Ap,
                                               const ushort* __restrict__ Bt,
                                               const float* __restrict__ bias,
                                               ushort* __restrict__ zb,
                                               void* __restrict__ yout,
                                               int gmb)
{
    constexpr int CB   = IS_L1 ? 4 : 2;        // 16-col fragments per wave
    constexpr int NCOL = IS_L1 ? 256 : 128;    // total output cols
    constexpr int ZW   = IS_L1 ? 128 : 64;     // z width
    __shared__ ushort As[64 * 128];            // 16 KB
    __shared__ ushort Bs[NCOL * 128];          // 64 KB (L1) / 32 KB (L2)

    const int tid = threadIdx.x;

    // ---- stage B panel once (swizzled, rows = output cols) ----
    for (int c = tid; c < NCOL * 16; c += 256) {
        int row  = c >> 4;
        int coff = (c & 15) * 8;
        short8 vb = *reinterpret_cast<const short8*>(Bt + (size_t)row * 128 + coff);
        int byte = row * 256 + coff * 2;
        byte ^= ((row & 7) << 4);
        *reinterpret_cast<short8*>(reinterpret_cast<char*>(Bs) + byte) = vb;
    }

    const int wid = tid >> 6, lane = tid & 63;
    const int lr  = lane & 15;
    const int lk  = (lane >> 4) << 3;
    const char* pA = reinterpret_cast<const char*>(As);
    const char* pB = reinterpret_cast<const char*>(Bs);

    for (int bm = blockIdx.x; bm < GMTILES; bm += gmb) {
        __syncthreads();   // iter0: cover Bs stage; later: protect As re-stage
        // ---- stage A tile (64 rows x K=128, swizzled) ----
        for (int c = tid; c < 1024; c += 256) {
            int row  = c >> 4;
            int coff = (c & 15) * 8;
            int gr   = bm * 64 + row;
            short8 va;
            if (gr < NN) {
                if (IS_L1) {
                    const float* A = (const float*)Ap;
                    float4 f0 = *reinterpret_cast<const float4*>(A + (size_t)gr * 128 + coff);
                    float4 f1 = *reinterpret_cast<const float4*>(A + (size_t)gr * 128 + coff + 4);
                    va[0] = (short)f2bf(f0.x); va[1] = (short)f2bf(f0.y);
                    va[2] = (short)f2bf(f0.z); va[3] = (short)f2bf(f0.w);
                    va[4] = (short)f2bf(f1.x); va[5] = (short)f2bf(f1.y);
                    va[6] = (short)f2bf(f1.z); va[7] = (short)f2bf(f1.w);
                } else {
                    const ushort* A = (const ushort*)Ap;
                    va = *reinterpret_cast<const short8*>(A + (size_t)gr * 128 + coff);
                }
            } else {
                va = short8{0, 0, 0, 0, 0, 0, 0, 0};
            }
            int byte = row * 256 + coff * 2;
            byte ^= ((row & 7) << 4);
            *reinterpret_cast<short8*>(reinterpret_cast<char*>(As) + byte) = va;
        }
        __syncthreads();

        f32x4 acc[4][CB];
#pragma unroll
        for (int mi = 0; mi < 4; ++mi)
#pragma unroll
            for (int nf = 0; nf < CB; ++nf) acc[mi][nf] = f32x4{0.f, 0.f, 0.f, 0.f};

#pragma unroll
        for (int ks = 0; ks < 4; ++ks) {
            int k2 = (ks * 32 + lk) * 2;
            short8 a[4], b[CB];
#pragma unroll
            for (int mi = 0; mi < 4; ++mi) {
                int r = mi * 16 + lr;
                int byte = r * 256 + k2;
                byte ^= ((r & 7) << 4);
                a[mi] = *reinterpret_cast<const short8*>(pA + byte);
            }
#pragma unroll
            for (int nf = 0; nf < CB; ++nf) {
                int colB = wid * (16 * CB) + nf * 16 + lr;
                int byte = colB * 256 + k2;
                byte ^= ((colB & 7) << 4);
                b[nf] = *reinterpret_cast<const short8*>(pB + byte);
            }
#pragma unroll
            for (int mi = 0; mi < 4; ++mi)
#pragma unroll
                for (int nf = 0; nf < CB; ++nf)
                    acc[mi][nf] = __builtin_amdgcn_mfma_f32_16x16x32_bf16(a[mi], b[nf], acc[mi][nf], 0, 0, 0);
        }

        // D mapping: col = lane&15, row = 4*(lane>>4) + reg
#pragma unroll
        for (int mi = 0; mi < 4; ++mi) {
#pragma unroll
            for (int nf = 0; nf < CB; ++nf) {
                int colg = wid * (16 * CB) + nf * 16 + lr;
#pragma unroll
                for (int rr = 0; rr < 4; ++rr) {
                    int rowg = bm * 64 + mi * 16 + ((lane >> 4) << 2) + rr;
                    if (rowg < NN) {
                        float v = acc[mi][nf][rr];
                        if (colg < ZW) {
                            zb[(size_t)rowg * ZW + colg] = f2bf(v);
                        } else {
                            int c2 = colg - ZW;
                            if (IS_L1) ((ushort*)yout)[(size_t)rowg * 128 + c2] = f2bf(v + bias[c2]);
                            else       ((float*)yout)[(size_t)rowg * 64 + c2]  = v + bias[c2];
                        }
                    }
                }
            }
        }
    }
}

// ---------------------------------------------------------------------------
// Gather 1: hb[n] = relu( mean z1b[nbrs] + y1b[n] )  (128-wide bf16)
// Wave per node; halves take alternate edges; uint2 loads (8B) -> one load
// round covers 2 edges; 8 edges per unrolled iteration; shfl_xor(32) merge.
// ---------------------------------------------------------------------------
__global__ __launch_bounds__(256) void k_gather1(const ushort* __restrict__ z1b,
                                                 const ushort* __restrict__ y1b,
                                                 const int* __restrict__ rowptr,
                                                 const int* __restrict__ col,
                                                 ushort* __restrict__ hb)
{
    const int w = threadIdx.x >> 6, lane = threadIdx.x & 63;
    const int n = blockIdx.x * 4 + w;
    if (n >= NN) return;
    const int half = lane >> 5, li = lane & 31;
    const int beg = rowptr[n], end = rowptr[n + 1];
    const uint2* zu = (const uint2*)z1b;      // row = 32 uint2
    float a0 = 0.f, a1 = 0.f, a2 = 0.f, a3 = 0.f;
    int e = beg;
    for (; e + 7 < end; e += 8) {
        int s0 = col[e     + half];
        int s1 = col[e + 2 + half];
        int s2 = col[e + 4 + half];
        int s3 = col[e + 6 + half];
        uint2 u0 = zu[(size_t)s0 * 32 + li];
        uint2 u1 = zu[(size_t)s1 * 32 + li];
        uint2 u2 = zu[(size_t)s2 * 32 + li];
        uint2 u3 = zu[(size_t)s3 * 32 + li];
        a0 += bflo(u0.x) + bflo(u1.x) + bflo(u2.x) + bflo(u3.x);
        a1 += bfhi(u0.x) + bfhi(u1.x) + bfhi(u2.x) + bfhi(u3.x);
        a2 += bflo(u0.y) + bflo(u1.y) + bflo(u2.y) + bflo(u3.y);
        a3 += bfhi(u0.y) + bfhi(u1.y) + bfhi(u2.y) + bfhi(u3.y);
    }
    for (; e + 1 < end; e += 2) {
        int s0 = col[e + half];
        uint2 u0 = zu[(size_t)s0 * 32 + li];
        a0 += bflo(u0.x); a1 += bfhi(u0.x);
        a2 += bflo(u0.y); a3 += bfhi(u0.y);
    }
    if (e < end && half == 0) {
        int s0 = col[e];
        uint2 u0 = zu[(size_t)s0 * 32 + li];
        a0 += bflo(u0.x); a1 += bfhi(u0.x);
        a2 += bflo(u0.y); a3 += bfhi(u0.y);
    }
    a0 += __shfl_xor(a0, 32); a1 += __shfl_xor(a1, 32);
    a2 += __shfl_xor(a2, 32); a3 += __shfl_xor(a3, 32);
    if (half == 0) {
        float inv = 1.0f / (float)max(end - beg, 1);
        uint2 uy = ((const uint2*)y1b)[(size_t)n * 32 + li];
        float h0 = fmaxf(a0 * inv + bflo(uy.x), 0.f);
        float h1 = fmaxf(a1 * inv + bfhi(uy.x), 0.f);
        float h2 = fmaxf(a2 * inv + bflo(uy.y), 0.f);
        float h3 = fmaxf(a3 * inv + bfhi(uy.y), 0.f);
        uint2 o;
        o.x = packbf(h0, h1);
        o.y = packbf(h2, h3);
        ((uint2*)hb)[(size_t)n * 32 + li] = o;
    }
}

// ---------------------------------------------------------------------------
// Gather 2: out[n] = mean z2b[nbrs] + y2f[n]  (64-wide, fp32 out)
// Wave per node; quarters take every 4th edge; uint2 loads -> 4 edges per
// load round; 16 edges per unrolled iteration; shfl_xor(16|32) merge.
// ---------------------------------------------------------------------------
__global__ __launch_bounds__(256) void k_gather2(const ushort* __restrict__ z2b,
                                                 const float* __restrict__ y2f,
                                                 const int* __restrict__ rowptr,
                                                 const int* __restrict__ col,
                                                 float* __restrict__ out)
{
    const int w = threadIdx.x >> 6, lane = threadIdx.x & 63;
    const int n = blockIdx.x * 4 + w;
    if (n >= NN) return;
    const int quar = lane >> 4, li = lane & 15;
    const int beg = rowptr[n], end = rowptr[n + 1];
    const uint2* zu = (const uint2*)z2b;      // row = 16 uint2
    float a0 = 0.f, a1 = 0.f, a2 = 0.f, a3 = 0.f;
    int e = beg;
    for (; e + 15 < end; e += 16) {
        int s0 = col[e      + quar];
        int s1 = col[e + 4  + quar];
        int s2 = col[e + 8  + quar];
        int s3 = col[e + 12 + quar];
        uint2 u0 = zu[(size_t)s0 * 16 + li];
        uint2 u1 = zu[(size_t)s1 * 16 + li];
        uint2 u2 = zu[(size_t)s2 * 16 + li];
        uint2 u3 = zu[(size_t)s3 * 16 + li];
        a0 += bflo(u0.x) + bflo(u1.x) + bflo(u2.x) + bflo(u3.x);
        a1 += bfhi(u0.x) + bfhi(u1.x) + bfhi(u2.x) + bfhi(u3.x);
        a2 += bflo(u0.y) + bflo(u1.y) + bflo(u2.y) + bflo(u3.y);
        a3 += bfhi(u0.y) + bfhi(u1.y) + bfhi(u2.y) + bfhi(u3.y);
    }
    for (; e + 3 < end; e += 4) {
        int s0 = col[e + quar];
        uint2 u0 = zu[(size_t)s0 * 16 + li];
        a0 += bflo(u0.x); a1 += bfhi(u0.x);
        a2 += bflo(u0.y); a3 += bfhi(u0.y);
    }
    int rem = end - e;
    if (quar < rem) {
        int s0 = col[e + quar];
        uint2 u0 = zu[(size_t)s0 * 16 + li];
        a0 += bflo(u0.x); a1 += bfhi(u0.x);
        a2 += bflo(u0.y); a3 += bfhi(u0.y);
    }
    a0 += __shfl_xor(a0, 16); a1 += __shfl_xor(a1, 16);
    a2 += __shfl_xor(a2, 16); a3 += __shfl_xor(a3, 16);
    a0 += __shfl_xor(a0, 32); a1 += __shfl_xor(a1, 32);
    a2 += __shfl_xor(a2, 32); a3 += __shfl_xor(a3, 32);
    if (quar == 0) {
        float inv = 1.0f / (float)max(end - beg, 1);
        float4 y = ((const float4*)y2f)[(size_t)n * 16 + li];
        float4 o;
        o.x = a0 * inv + y.x;
        o.y = a1 * inv + y.y;
        o.z = a2 * inv + y.z;
        o.w = a3 * inv + y.w;
        ((float4*)out)[(size_t)n * 16 + li] = o;
    }
}

extern "C" void kernel_launch(void* const* d_in, const int* in_sizes, int n_in,
                              void* d_out, int out_size, void* d_ws, size_t ws_size,
                              hipStream_t stream)
{
    const float* x   = (const float*)d_in[0];
    const int*   ei  = (const int*)d_in[1];
    const float* W1l = (const float*)d_in[2];
    const float* W1r = (const float*)d_in[3];
    const float* b1  = (const float*)d_in[4];
    const float* W2l = (const float*)d_in[5];
    const float* W2r = (const float*)d_in[6];
    const float* b2  = (const float*)d_in[7];
    float* out = (float*)d_out;

    const int* src = ei;
    const int* dst = ei + NE;

    // workspace layout
    int*  rowptr = (int*)d_ws;                      // NN+1
    int*  pcnt   = rowptr + NN + 1;                 // 256
    int*  poff   = pcnt + 256;                      // 256 (NP+1 used)
    int*  gcur   = poff + 256;                      // 256
    uint* packed = (uint*)(gcur + 256);             // NE
    int*  colA   = (int*)(packed + NE);             // NE
    uintptr_t p = (uintptr_t)(colA + NE);
    p = (p + 255) & ~(uintptr_t)255;
    ushort* WbT1 = (ushort*)p;  p += (size_t)256 * 128 * 2;
    ushort* WbT2 = (ushort*)p;  p += (size_t)128 * 128 * 2;
    p = (p + 255) & ~(uintptr_t)255;
    ushort* z1b = (ushort*)p;   p += (size_t)NN * 128 * 2;  // row-major bf16
    ushort* y1b = (ushort*)p;   p += (size_t)NN * 128 * 2;  // row-major bf16
    ushort* hb  = (ushort*)p;   p += (size_t)NN * 128 * 2;  // row-major bf16
    ushort* z2b = z1b;                              // [NN][64] bf16, alias
    float*  y2f = (float*)y1b;                      // [NN][64] fp32, alias

    // ---- CSR build (partition-local) ----
    hipMemsetAsync(pcnt, 0, 256 * sizeof(int), stream);
    k_phist<<<NBIN, 256, 0, stream>>>(dst, pcnt);
    k_pscan<<<1, 256, 0, stream>>>(pcnt, poff, gcur, rowptr);
    k_binning<<<NBIN, 256, 0, stream>>>(src, dst, gcur, packed);
    k_pfill<<<NP, 256, 0, stream>>>(packed, poff, rowptr, colA);

    // ---- weights to bf16 (transposed) ----
    k_castw<<<(256 * 128 + 128 * 128 + 255) / 256, 256, 0, stream>>>(
        W1l, W1r, W2l, W2r, WbT1, WbT2);

    // ---- layer 1 ----  (80KB LDS -> 2 blocks/CU; 512 blocks fill exactly)
    k_gemmf<true><<<512, 256, 0, stream>>>(x, WbT1, b1, z1b, y1b, 512);
    k_gather1<<<(NN + 3) / 4, 256, 0, stream>>>(z1b, y1b, rowptr, colA, hb);

    // ---- layer 2 ----  (48KB LDS -> 3 blocks/CU; 768 blocks fill exactly)
    k_gemmf<false><<<768, 256, 0, stream>>>(hb, WbT2, b2, z2b, y2f, 768);
    k_gather2<<<(NN + 3) / 4, 256, 0, stream>>>(z2b, y2f, rowptr, colA, out);
}

// Round 9
// 267.978 us; speedup vs baseline: 1.0415x; 1.0415x over previous
//
#include <hip/hip_runtime.h>

#define NN 100000
#define NE 1600000
#define PSHIFT 9
#define PSZ 512
#define NP ((NN + PSZ - 1) / PSZ)             // 196
#define BCHUNK 8192
#define NBIN ((NE + BCHUNK - 1) / BCHUNK)     // 196
#define SRCMASK 0x1FFFF                       // 17 bits (NN < 131072)
#define GMTILES ((NN + 63) / 64)              // 1563
#define GEMM_GB 512                           // gemm grid (blocks), grid-stride

typedef __attribute__((ext_vector_type(8))) short short8;
typedef __attribute__((ext_vector_type(4))) float f32x4;

__device__ __forceinline__ ushort f2bf(float f) {
    uint u = __float_as_uint(f);
    return (ushort)((u + 0x7FFFu + ((u >> 16) & 1u)) >> 16);   // RNE
}
__device__ __forceinline__ float bflo(uint u) { return __uint_as_float(u << 16); }
__device__ __forceinline__ float bfhi(uint u) { return __uint_as_float(u & 0xffff0000u); }
__device__ __forceinline__ uint packbf(float a, float b) {
    return (uint)f2bf(a) | ((uint)f2bf(b) << 16);
}

// ---------------------------------------------------------------------------
// CSR build, partition-local for write locality (round-4 proven).
// ---------------------------------------------------------------------------
__global__ __launch_bounds__(256) void k_phist(const int* __restrict__ dst,
                                               int* __restrict__ pcnt)
{
    __shared__ int cnt[256];
    const int tid = threadIdx.x;
    cnt[tid] = 0;
    __syncthreads();
    const long e0 = (long)blockIdx.x * BCHUNK;
    for (int i = tid; i < BCHUNK; i += 256) {
        long e = e0 + i;
        if (e < NE) atomicAdd(&cnt[dst[e] >> PSHIFT], 1);
    }
    __syncthreads();
    if (cnt[tid] > 0) atomicAdd(&pcnt[tid], cnt[tid]);
}

__global__ __launch_bounds__(256) void k_pscan(const int* __restrict__ pcnt,
                                               int* __restrict__ poff,
                                               int* __restrict__ gcur,
                                               int* __restrict__ rowptr)
{
    __shared__ int tmp[256];
    const int tid = threadIdx.x;
    int v = (tid < NP) ? pcnt[tid] : 0;
    tmp[tid] = v;
    __syncthreads();
    for (int off = 1; off < 256; off <<= 1) {
        int t = (tid >= off) ? tmp[tid - off] : 0;
        __syncthreads();
        tmp[tid] += t;
        __syncthreads();
    }
    int ex = tmp[tid] - v;
    if (tid < NP) { poff[tid] = ex; gcur[tid] = ex; }
    if (tid == 0) { poff[NP] = NE; rowptr[NN] = NE; }
}

__global__ __launch_bounds__(256) void k_binning(const int* __restrict__ src,
                                                 const int* __restrict__ dst,
                                                 int* __restrict__ gcur,
                                                 uint* __restrict__ packed)
{
    __shared__ int cnt[256];
    __shared__ int base[256];
    const int tid = threadIdx.x;
    const long e0 = (long)blockIdx.x * BCHUNK;
    cnt[tid] = 0;
    __syncthreads();
    for (int i = tid; i < BCHUNK; i += 256) {
        long e = e0 + i;
        if (e < NE) atomicAdd(&cnt[dst[e] >> PSHIFT], 1);
    }
    __syncthreads();
    if (cnt[tid] > 0) base[tid] = atomicAdd(&gcur[tid], cnt[tid]);
    cnt[tid] = 0;
    __syncthreads();
    for (int i = tid; i < BCHUNK; i += 256) {
        long e = e0 + i;
        if (e < NE) {
            int d = dst[e], s = src[e];
            int p = d >> PSHIFT;
            int ofs = atomicAdd(&cnt[p], 1);
            packed[base[p] + ofs] = (uint)s | ((uint)(d & (PSZ - 1)) << 17);
        }
    }
}

__global__ __launch_bounds__(256) void k_pfill(const uint* __restrict__ packed,
                                               const int* __restrict__ poff,
                                               int* __restrict__ rowptr,
                                               int* __restrict__ col)
{
    __shared__ int cnt[PSZ];
    __shared__ int cur[PSZ];
    __shared__ int tot[256];
    const int p   = blockIdx.x;
    const int tid = threadIdx.x;
    const int beg = poff[p], end = poff[p + 1];
    cnt[tid] = 0; cnt[tid + 256] = 0;
    __syncthreads();
    for (int i = beg + tid; i < end; i += 256)
        atomicAdd(&cnt[packed[i] >> 17], 1);
    __syncthreads();
    int v0 = cnt[tid * 2], v1 = cnt[tid * 2 + 1];
    int s  = v0 + v1;
    tot[tid] = s;
    __syncthreads();
    for (int off = 1; off < 256; off <<= 1) {
        int t = (tid >= off) ? tot[tid - off] : 0;
        __syncthreads();
        tot[tid] += t;
        __syncthreads();
    }
    int ex = tot[tid] - s + beg;
    cur[tid * 2]     = ex;
    cur[tid * 2 + 1] = ex + v0;
    int n0 = p * PSZ;
    if (n0 + tid * 2     < NN) rowptr[n0 + tid * 2]     = ex;
    if (n0 + tid * 2 + 1 < NN) rowptr[n0 + tid * 2 + 1] = ex + v0;
    __syncthreads();
    for (int i = beg + tid; i < end; i += 256) {
        uint v = packed[i];
        int pos = atomicAdd(&cur[v >> 17], 1);
        col[pos] = (int)(v & SRCMASK);
    }
}

// ---------------------------------------------------------------------------
// Weight prep: WbT1[256][128] = [W1_l | W1_r]^T bf16; WbT2[128][128]
// ---------------------------------------------------------------------------
__global__ __launch_bounds__(256) void k_castw(const float* __restrict__ W1l,
                                               const float* __restrict__ W1r,
                                               const float* __restrict__ W2l,
                                               const float* __restrict__ W2r,
                                               ushort* __restrict__ WbT1,
                                               ushort* __restrict__ WbT2)
{
    int i = blockIdx.x * 256 + threadIdx.x;
    if (i < 256 * 128) {
        int c = i >> 7, k = i & 127;
        float v = (c < 128) ? W1l[k * 128 + c] : W1r[k * 128 + (c - 128)];
        WbT1[i] = f2bf(v);
    } else if (i < 256 * 128 + 128 * 128) {
        int j = i - 256 * 128;
        int c = j >> 7, k = j & 127;
        float v = (c < 64) ? W2l[k * 64 + c] : W2r[k * 64 + (c - 64)];
        WbT2[j] = f2bf(v);
    }
}

// ---------------------------------------------------------------------------
// x fp32 -> bf16 cast (streaming, vectorized: 2x float4 in, short8 out)
// ---------------------------------------------------------------------------
__global__ __launch_bounds__(256) void k_castx(const float* __restrict__ x,
                                               ushort* __restrict__ xb)
{
    const int CH = NN * 16;                   // 16B output chunks (8 elems)
    for (int i = blockIdx.x * 256 + threadIdx.x; i < CH; i += 256 * 2048) {
        float4 f0 = ((const float4*)x)[(size_t)i * 2];
        float4 f1 = ((const float4*)x)[(size_t)i * 2 + 1];
        short8 v;
        v[0] = (short)f2bf(f0.x); v[1] = (short)f2bf(f0.y);
        v[2] = (short)f2bf(f0.z); v[3] = (short)f2bf(f0.w);
        v[4] = (short)f2bf(f1.x); v[5] = (short)f2bf(f1.y);
        v[6] = (short)f2bf(f1.z); v[7] = (short)f2bf(f1.w);
        ((short8*)xb)[i] = v;
    }
}

// ---------------------------------------------------------------------------
// Pipelined dual-GEMM: [z | y] = A @ [Wl | Wr] (+bias on y half).
// A bf16 [NN][128]. 512 threads = 8 waves; wave owns 16*CB output cols.
// B fragments in REGISTERS (loaded once per block; invariant across tiles).
// A tile 64x128 double-buffered in swizzled LDS; T14 schedule:
//   ds_write(t) -> barrier -> issue loads(t+GB) -> MFMA(t)+stores -> flip.
// ---------------------------------------------------------------------------
template <int CB, int NCOL, bool YF32>
__global__ __launch_bounds__(512) void k_gemm(const ushort* __restrict__ Ab,
                                              const ushort* __restrict__ Bt,
                                              const float* __restrict__ bias,
                                              ushort* __restrict__ zb,
                                              void* __restrict__ yout)
{
    constexpr int ZW = NCOL / 2;               // z width == y width
    __shared__ ushort As[2][64 * 128];         // 2 x 16 KB

    const int tid  = threadIdx.x;
    const int wid  = tid >> 6, lane = tid & 63;
    const int lr   = lane & 15;
    const int lk   = (lane >> 4) << 3;

    // ---- B fragments -> registers (one-time; Bt is L2-resident) ----
    short8 bfr[4][CB];
#pragma unroll
    for (int ks = 0; ks < 4; ++ks)
#pragma unroll
        for (int nf = 0; nf < CB; ++nf) {
            int colB = wid * (16 * CB) + nf * 16 + lr;
            bfr[ks][nf] = *reinterpret_cast<const short8*>(
                Bt + (size_t)colB * 128 + ks * 32 + lk);
        }

    // staging geometry: 16 KB tile, thread covers bytes p0 and p0+8192
    const int p0 = tid * 16, p1 = p0 + 8192;
    const int r0 = p0 >> 8, r1 = p1 >> 8;      // tile-local row (256B rows)
    const int d0 = p0 ^ ((r0 & 7) << 4);       // swizzled LDS byte offset
    const int d1 = p1 ^ ((r1 & 7) << 4);
    const int e0 = (p0 & 255) >> 1;            // element offset in row
    const int e1 = (p1 & 255) >> 1;

    const short8 zero8 = {0, 0, 0, 0, 0, 0, 0, 0};
    short8 sA0, sA1;

    int t = blockIdx.x;
    {   // prologue loads (tile t)
        int gr0 = t * 64 + r0, gr1 = t * 64 + r1;
        sA0 = (gr0 < NN) ? *reinterpret_cast<const short8*>(Ab + (size_t)gr0 * 128 + e0) : zero8;
        sA1 = (gr1 < NN) ? *reinterpret_cast<const short8*>(Ab + (size_t)gr1 * 128 + e1) : zero8;
    }

    int cur = 0;
    for (; t < GMTILES; t += GEMM_GB) {
        char* wbase = reinterpret_cast<char*>(As[cur]);
        *reinterpret_cast<short8*>(wbase + d0) = sA0;
        *reinterpret_cast<short8*>(wbase + d1) = sA1;
        __syncthreads();

        int tn = t + GEMM_GB;
        if (tn < GMTILES) {                    // issue next-tile loads NOW
            int gr0 = tn * 64 + r0, gr1 = tn * 64 + r1;
            sA0 = (gr0 < NN) ? *reinterpret_cast<const short8*>(Ab + (size_t)gr0 * 128 + e0) : zero8;
            sA1 = (gr1 < NN) ? *reinterpret_cast<const short8*>(Ab + (size_t)gr1 * 128 + e1) : zero8;
        }

        f32x4 acc[4][CB];
#pragma unroll
        for (int mi = 0; mi < 4; ++mi)
#pragma unroll
            for (int nf = 0; nf < CB; ++nf) acc[mi][nf] = f32x4{0.f, 0.f, 0.f, 0.f};

        const char* pA = reinterpret_cast<const char*>(As[cur]);
#pragma unroll
        for (int ks = 0; ks < 4; ++ks) {
            int k2 = (ks * 32 + lk) * 2;
            short8 a[4];
#pragma unroll
            for (int mi = 0; mi < 4; ++mi) {
                int r = mi * 16 + lr;
                int byte = (r * 256 + k2) ^ ((r & 7) << 4);
                a[mi] = *reinterpret_cast<const short8*>(pA + byte);
            }
#pragma unroll
            for (int mi = 0; mi < 4; ++mi)
#pragma unroll
                for (int nf = 0; nf < CB; ++nf)
                    acc[mi][nf] = __builtin_amdgcn_mfma_f32_16x16x32_bf16(
                        a[mi], bfr[ks][nf], acc[mi][nf], 0, 0, 0);
        }

        // epilogue: D col = lane&15, row = 4*(lane>>4) + reg
#pragma unroll
        for (int mi = 0; mi < 4; ++mi) {
#pragma unroll
            for (int nf = 0; nf < CB; ++nf) {
                int colg = wid * (16 * CB) + nf * 16 + lr;
#pragma unroll
                for (int rr = 0; rr < 4; ++rr) {
                    int rowg = t * 64 + mi * 16 + ((lane >> 4) << 2) + rr;
                    if (rowg < NN) {
                        float v = acc[mi][nf][rr];
                        if (colg < ZW) {
                            zb[(size_t)rowg * ZW + colg] = f2bf(v);
                        } else {
                            int c2 = colg - ZW;
                            if (YF32) ((float*)yout)[(size_t)rowg * ZW + c2]  = v + bias[c2];
                            else      ((ushort*)yout)[(size_t)rowg * ZW + c2] = f2bf(v + bias[c2]);
                        }
                    }
                }
            }
        }
        cur ^= 1;
    }
}

// ---------------------------------------------------------------------------
// Gather 1: hb[n] = relu( mean z1b[nbrs] + y1b[n] )  (128-wide bf16)
// Wave per node; halves take alternate edges; uint2 loads (8B).
// ---------------------------------------------------------------------------
__global__ __launch_bounds__(256) void k_gather1(const ushort* __restrict__ z1b,
                                                 const ushort* __restrict__ y1b,
                                                 const int* __restrict__ rowptr,
                                                 const int* __restrict__ col,
                                                 ushort* __restrict__ hb)
{
    const int w = threadIdx.x >> 6, lane = threadIdx.x & 63;
    const int n = blockIdx.x * 4 + w;
    if (n >= NN) return;
    const int half = lane >> 5, li = lane & 31;
    const int beg = rowptr[n], end = rowptr[n + 1];
    const uint2* zu = (const uint2*)z1b;      // row = 32 uint2
    float a0 = 0.f, a1 = 0.f, a2 = 0.f, a3 = 0.f;
    int e = beg;
    for (; e + 7 < end; e += 8) {
        int s0 = col[e     + half];
        int s1 = col[e + 2 + half];
        int s2 = col[e + 4 + half];
        int s3 = col[e + 6 + half];
        uint2 u0 = zu[(size_t)s0 * 32 + li];
        uint2 u1 = zu[(size_t)s1 * 32 + li];
        uint2 u2 = zu[(size_t)s2 * 32 + li];
        uint2 u3 = zu[(size_t)s3 * 32 + li];
        a0 += bflo(u0.x) + bflo(u1.x) + bflo(u2.x) + bflo(u3.x);
        a1 += bfhi(u0.x) + bfhi(u1.x) + bfhi(u2.x) + bfhi(u3.x);
        a2 += bflo(u0.y) + bflo(u1.y) + bflo(u2.y) + bflo(u3.y);
        a3 += bfhi(u0.y) + bfhi(u1.y) + bfhi(u2.y) + bfhi(u3.y);
    }
    for (; e + 1 < end; e += 2) {
        int s0 = col[e + half];
        uint2 u0 = zu[(size_t)s0 * 32 + li];
        a0 += bflo(u0.x); a1 += bfhi(u0.x);
        a2 += bflo(u0.y); a3 += bfhi(u0.y);
    }
    if (e < end && half == 0) {
        int s0 = col[e];
        uint2 u0 = zu[(size_t)s0 * 32 + li];
        a0 += bflo(u0.x); a1 += bfhi(u0.x);
        a2 += bflo(u0.y); a3 += bfhi(u0.y);
    }
    a0 += __shfl_xor(a0, 32); a1 += __shfl_xor(a1, 32);
    a2 += __shfl_xor(a2, 32); a3 += __shfl_xor(a3, 32);
    if (half == 0) {
        float inv = 1.0f / (float)max(end - beg, 1);
        uint2 uy = ((const uint2*)y1b)[(size_t)n * 32 + li];
        float h0 = fmaxf(a0 * inv + bflo(uy.x), 0.f);
        float h1 = fmaxf(a1 * inv + bfhi(uy.x), 0.f);
        float h2 = fmaxf(a2 * inv + bflo(uy.y), 0.f);
        float h3 = fmaxf(a3 * inv + bfhi(uy.y), 0.f);
        uint2 o;
        o.x = packbf(h0, h1);
        o.y = packbf(h2, h3);
        ((uint2*)hb)[(size_t)n * 32 + li] = o;
    }
}

// ---------------------------------------------------------------------------
// Gather 2: out[n] = mean z2b[nbrs] + y2f[n]  (64-wide, fp32 out)
// Wave per node; quarters take every 4th edge; uint2 loads.
// ---------------------------------------------------------------------------
__global__ __launch_bounds__(256) void k_gather2(const ushort* __restrict__ z2b,
                                                 const float* __restrict__ y2f,
                                                 const int* __restrict__ rowptr,
                                                 const int* __restrict__ col,
                                                 float* __restrict__ out)
{
    const int w = threadIdx.x >> 6, lane = threadIdx.x & 63;
    const int n = blockIdx.x * 4 + w;
    if (n >= NN) return;
    const int quar = lane >> 4, li = lane & 15;
    const int beg = rowptr[n], end = rowptr[n + 1];
    const uint2* zu = (const uint2*)z2b;      // row = 16 uint2
    float a0 = 0.f, a1 = 0.f, a2 = 0.f, a3 = 0.f;
    int e = beg;
    for (; e + 15 < end; e += 16) {
        int s0 = col[e      + quar];
        int s1 = col[e + 4  + quar];
        int s2 = col[e + 8  + quar];
        int s3 = col[e + 12 + quar];
        uint2 u0 = zu[(size_t)s0 * 16 + li];
        uint2 u1 = zu[(size_t)s1 * 16 + li];
        uint2 u2 = zu[(size_t)s2 * 16 + li];
        uint2 u3 = zu[(size_t)s3 * 16 + li];
        a0 += bflo(u0.x) + bflo(u1.x) + bflo(u2.x) + bflo(u3.x);
        a1 += bfhi(u0.x) + bfhi(u1.x) + bfhi(u2.x) + bfhi(u3.x);
        a2 += bflo(u0.y) + bflo(u1.y) + bflo(u2.y) + bflo(u3.y);
        a3 += bfhi(u0.y) + bfhi(u1.y) + bfhi(u2.y) + bfhi(u3.y);
    }
    for (; e + 3 < end; e += 4) {
        int s0 = col[e + quar];
        uint2 u0 = zu[(size_t)s0 * 16 + li];
        a0 += bflo(u0.x); a1 += bfhi(u0.x);
        a2 += bflo(u0.y); a3 += bfhi(u0.y);
    }
    int rem = end - e;
    if (quar < rem) {
        int s0 = col[e + quar];
        uint2 u0 = zu[(size_t)s0 * 16 + li];
        a0 += bflo(u0.x); a1 += bfhi(u0.x);
        a2 += bflo(u0.y); a3 += bfhi(u0.y);
    }
    a0 += __shfl_xor(a0, 16); a1 += __shfl_xor(a1, 16);
    a2 += __shfl_xor(a2, 16); a3 += __shfl_xor(a3, 16);
    a0 += __shfl_xor(a0, 32); a1 += __shfl_xor(a1, 32);
    a2 += __shfl_xor(a2, 32); a3 += __shfl_xor(a3, 32);
    if (quar == 0) {
        float inv = 1.0f / (float)max(end - beg, 1);
        float4 y = ((const float4*)y2f)[(size_t)n * 16 + li];
        float4 o;
        o.x = a0 * inv + y.x;
        o.y = a1 * inv + y.y;
        o.z = a2 * inv + y.z;
        o.w = a3 * inv + y.w;
        ((float4*)out)[(size_t)n * 16 + li] = o;
    }
}

extern "C" void kernel_launch(void* const* d_in, const int* in_sizes, int n_in,
                              void* d_out, int out_size, void* d_ws, size_t ws_size,
                              hipStream_t stream)
{
    const float* x   = (const float*)d_in[0];
    const int*   ei  = (const int*)d_in[1];
    const float* W1l = (const float*)d_in[2];
    const float* W1r = (const float*)d_in[3];
    const float* b1  = (const float*)d_in[4];
    const float* W2l = (const float*)d_in[5];
    const float* W2r = (const float*)d_in[6];
    const float* b2  = (const float*)d_in[7];
    float* out = (float*)d_out;

    const int* src = ei;
    const int* dst = ei + NE;

    // workspace layout
    int*  rowptr = (int*)d_ws;                      // NN+1
    int*  pcnt   = rowptr + NN + 1;                 // 256
    int*  poff   = pcnt + 256;                      // 256 (NP+1 used)
    int*  gcur   = poff + 256;                      // 256
    uint* packed = (uint*)(gcur + 256);             // NE
    int*  colA   = (int*)(packed + NE);             // NE
    uintptr_t p = (uintptr_t)(colA + NE);
    p = (p + 255) & ~(uintptr_t)255;
    ushort* WbT1 = (ushort*)p;  p += (size_t)256 * 128 * 2;
    ushort* WbT2 = (ushort*)p;  p += (size_t)128 * 128 * 2;
    p = (p + 255) & ~(uintptr_t)255;
    ushort* xb  = (ushort*)p;   p += (size_t)NN * 128 * 2;  // x in bf16
    ushort* z1b = (ushort*)p;   p += (size_t)NN * 128 * 2;  // row-major bf16
    ushort* y1b = (ushort*)p;   p += (size_t)NN * 128 * 2;  // row-major bf16
    ushort* hb  = (ushort*)p;   p += (size_t)NN * 128 * 2;  // row-major bf16
    ushort* z2b = z1b;                              // [NN][64] bf16, alias
    float*  y2f = (float*)y1b;                      // [NN][64] fp32, alias

    // ---- CSR build (partition-local) ----
    hipMemsetAsync(pcnt, 0, 256 * sizeof(int), stream);
    k_phist<<<NBIN, 256, 0, stream>>>(dst, pcnt);
    k_pscan<<<1, 256, 0, stream>>>(pcnt, poff, gcur, rowptr);
    k_binning<<<NBIN, 256, 0, stream>>>(src, dst, gcur, packed);
    k_pfill<<<NP, 256, 0, stream>>>(packed, poff, rowptr, colA);

    // ---- weight + x casts ----
    k_castw<<<(256 * 128 + 128 * 128 + 255) / 256, 256, 0, stream>>>(
        W1l, W1r, W2l, W2r, WbT1, WbT2);
    k_castx<<<2048, 256, 0, stream>>>(x, xb);

    // ---- layer 1 ----
    k_gemm<2, 256, false><<<GEMM_GB, 512, 0, stream>>>(xb, WbT1, b1, z1b, y1b);
    k_gather1<<<(NN + 3) / 4, 256, 0, stream>>>(z1b, y1b, rowptr, colA, hb);

    // ---- layer 2 ----
    k_gemm<1, 128, true><<<GEMM_GB, 512, 0, stream>>>(hb, WbT2, b2, z2b, y2f);
    k_gather2<<<(NN + 3) / 4, 256, 0, stream>>>(z2b, y2f, rowptr, colA, out);
}

// Round 10
// 239.984 us; speedup vs baseline: 1.1630x; 1.1167x over previous
//
#include <hip/hip_runtime.h>

#define NN 100000
#define NE 1600000
#define PSHIFT 9
#define PSZ 512
#define NP ((NN + PSZ - 1) / PSZ)             // 196
#define BCHUNK 8192
#define NBIN ((NE + BCHUNK - 1) / BCHUNK)     // 196
#define SRCMASK 0x1FFFF                       // 17 bits (NN < 131072)
#define BUCKET 9216                           // per-partition col slots (λ=8192, +11σ)
#define GMTILES ((NN + 63) / 64)              // 1563
#define GEMM_GB 512                           // gemm grid (blocks), grid-stride

typedef __attribute__((ext_vector_type(8))) short short8;
typedef __attribute__((ext_vector_type(4))) float f32x4;

__device__ __forceinline__ ushort f2bf(float f) {
    uint u = __float_as_uint(f);
    return (ushort)((u + 0x7FFFu + ((u >> 16) & 1u)) >> 16);   // RNE
}
__device__ __forceinline__ float bflo(uint u) { return __uint_as_float(u << 16); }
__device__ __forceinline__ float bfhi(uint u) { return __uint_as_float(u & 0xffff0000u); }
__device__ __forceinline__ uint packbf(float a, float b) {
    return (uint)f2bf(a) | ((uint)f2bf(b) << 16);
}

// ---------------------------------------------------------------------------
// Prep: block 0 inits gcur[p] = p*BUCKET; blocks 1.. cast weights to bf16.
// WbT1[256][128] = [W1_l | W1_r]^T; WbT2[128][128] = [W2_l | W2_r]^T.
// ---------------------------------------------------------------------------
__global__ __launch_bounds__(256) void k_prep(const float* __restrict__ W1l,
                                              const float* __restrict__ W1r,
                                              const float* __restrict__ W2l,
                                              const float* __restrict__ W2r,
                                              ushort* __restrict__ WbT1,
                                              ushort* __restrict__ WbT2,
                                              int* __restrict__ gcur)
{
    const int tid = threadIdx.x;
    if (blockIdx.x == 0) {
        if (tid < NP) gcur[tid] = tid * BUCKET;
        return;
    }
    int i = (blockIdx.x - 1) * 256 + tid;
    if (i < 256 * 128) {
        int c = i >> 7, k = i & 127;
        float v = (c < 128) ? W1l[k * 128 + c] : W1r[k * 128 + (c - 128)];
        WbT1[i] = f2bf(v);
    } else if (i < 256 * 128 + 128 * 128) {
        int j = i - 256 * 128;
        int c = j >> 7, k = j & 127;
        float v = (c < 64) ? W2l[k * 64 + c] : W2r[k * 64 + (c - 64)];
        WbT2[j] = f2bf(v);
    }
}

// ---------------------------------------------------------------------------
// Binning: per-block LDS histogram of partition, one global atomic per
// (block, partition) to grab a run in the partition's fixed bucket, then
// write packed = src | (dlocal << 17).
// ---------------------------------------------------------------------------
__global__ __launch_bounds__(256) void k_binning(const int* __restrict__ src,
                                                 const int* __restrict__ dst,
                                                 int* __restrict__ gcur,
                                                 uint* __restrict__ packed)
{
    __shared__ int cnt[256];
    __shared__ int base[256];
    const int tid = threadIdx.x;
    const long e0 = (long)blockIdx.x * BCHUNK;
    cnt[tid] = 0;
    __syncthreads();
    for (int i = tid; i < BCHUNK; i += 256) {
        long e = e0 + i;
        if (e < NE) atomicAdd(&cnt[dst[e] >> PSHIFT], 1);
    }
    __syncthreads();
    if (cnt[tid] > 0) base[tid] = atomicAdd(&gcur[tid], cnt[tid]);
    cnt[tid] = 0;                       // reuse as run cursor
    __syncthreads();
    for (int i = tid; i < BCHUNK; i += 256) {
        long e = e0 + i;
        if (e < NE) {
            int d = dst[e], s = src[e];
            int p = d >> PSHIFT;
            int ofs = atomicAdd(&cnt[p], 1);
            packed[base[p] + ofs] = (uint)s | ((uint)(d & (PSZ - 1)) << 17);
        }
    }
}

// ---------------------------------------------------------------------------
// Per-partition fill: count 512 local nodes, scan, write rowptr/rowend,
// place col within the partition's bucket [p*BUCKET, gcur[p]).
// ---------------------------------------------------------------------------
__global__ __launch_bounds__(256) void k_pfill(const uint* __restrict__ packed,
                                               const int* __restrict__ gcur,
                                               int* __restrict__ rowptr,
                                               int* __restrict__ rowend,
                                               int* __restrict__ col)
{
    __shared__ int cnt[PSZ];
    __shared__ int cur[PSZ];
    __shared__ int tot[256];
    const int p   = blockIdx.x;
    const int tid = threadIdx.x;
    const int beg = p * BUCKET, end = gcur[p];
    cnt[tid] = 0; cnt[tid + 256] = 0;
    __syncthreads();
    for (int i = beg + tid; i < end; i += 256)
        atomicAdd(&cnt[packed[i] >> 17], 1);
    __syncthreads();
    int v0 = cnt[tid * 2], v1 = cnt[tid * 2 + 1];
    int s  = v0 + v1;
    tot[tid] = s;
    __syncthreads();
    for (int off = 1; off < 256; off <<= 1) {
        int t = (tid >= off) ? tot[tid - off] : 0;
        __syncthreads();
        tot[tid] += t;
        __syncthreads();
    }
    int ex = tot[tid] - s + beg;
    cur[tid * 2]     = ex;
    cur[tid * 2 + 1] = ex + v0;
    int n0 = p * PSZ;
    if (n0 + tid * 2 < NN) {
        rowptr[n0 + tid * 2] = ex;
        rowend[n0 + tid * 2] = ex + v0;
    }
    if (n0 + tid * 2 + 1 < NN) {
        rowptr[n0 + tid * 2 + 1] = ex + v0;
        rowend[n0 + tid * 2 + 1] = ex + v0 + v1;
    }
    __syncthreads();
    for (int i = beg + tid; i < end; i += 256) {
        uint v = packed[i];
        int pos = atomicAdd(&cur[v >> 17], 1);
        col[pos] = (int)(v & SRCMASK);
    }
}

// ---------------------------------------------------------------------------
// Pipelined dual-GEMM: [z | y] = A @ [Wl | Wr] (+bias on y half).
// 512 threads = 8 waves; wave owns 16*CB output cols; B fragments in
// registers (invariant across m-tiles); A 64x128 tile double-buffered in
// swizzled LDS with T14 split (write -> barrier -> issue next loads -> MFMA).
// AF32: A is fp32, converted during staging.
// ---------------------------------------------------------------------------
template <bool AF32, int CB, bool YF32>
__global__ __launch_bounds__(512) void k_gemm(const void* __restrict__ Ap,
                                              const ushort* __restrict__ Bt,
                                              const float* __restrict__ bias,
                                              ushort* __restrict__ zb,
                                              void* __restrict__ yout)
{
    constexpr int ZW = CB * 64;                // z width == y width (CB=2:128, CB=1:64)
    __shared__ ushort As[2][64 * 128];         // 2 x 16 KB

    const int tid  = threadIdx.x;
    const int wid  = tid >> 6, lane = tid & 63;
    const int lr   = lane & 15;
    const int lk   = (lane >> 4) << 3;

    // ---- B fragments -> registers (one-time; Bt is L2-resident) ----
    short8 bfr[4][CB];
#pragma unroll
    for (int ks = 0; ks < 4; ++ks)
#pragma unroll
        for (int nf = 0; nf < CB; ++nf) {
            int colB = wid * (16 * CB) + nf * 16 + lr;
            bfr[ks][nf] = *reinterpret_cast<const short8*>(
                Bt + (size_t)colB * 128 + ks * 32 + lk);
        }

    // staging geometry: 16 KB tile, thread covers bytes p0 and p0+8192
    const int p0 = tid * 16, p1 = p0 + 8192;
    const int r0 = p0 >> 8, r1 = p1 >> 8;      // tile-local row (256B rows)
    const int d0 = p0 ^ ((r0 & 7) << 4);       // swizzled LDS byte offset
    const int d1 = p1 ^ ((r1 & 7) << 4);
    const int e0 = (p0 & 255) >> 1;            // element offset in row
    const int e1 = (p1 & 255) >> 1;

    const short8 zero8 = {0, 0, 0, 0, 0, 0, 0, 0};
    short8 sA0, sA1;

    auto loadA = [&](int gr, int eo) -> short8 {
        if (gr >= NN) return zero8;
        if (AF32) {
            const float* A = (const float*)Ap;
            float4 f0 = *reinterpret_cast<const float4*>(A + (size_t)gr * 128 + eo);
            float4 f1 = *reinterpret_cast<const float4*>(A + (size_t)gr * 128 + eo + 4);
            short8 v;
            v[0] = (short)f2bf(f0.x); v[1] = (short)f2bf(f0.y);
            v[2] = (short)f2bf(f0.z); v[3] = (short)f2bf(f0.w);
            v[4] = (short)f2bf(f1.x); v[5] = (short)f2bf(f1.y);
            v[6] = (short)f2bf(f1.z); v[7] = (short)f2bf(f1.w);
            return v;
        } else {
            const ushort* A = (const ushort*)Ap;
            return *reinterpret_cast<const short8*>(A + (size_t)gr * 128 + eo);
        }
    };

    int t = blockIdx.x;
    sA0 = loadA(t * 64 + r0, e0);              // prologue loads (tile t)
    sA1 = loadA(t * 64 + r1, e1);

    int cur = 0;
    for (; t < GMTILES; t += GEMM_GB) {
        char* wbase = reinterpret_cast<char*>(As[cur]);
        *reinterpret_cast<short8*>(wbase + d0) = sA0;
        *reinterpret_cast<short8*>(wbase + d1) = sA1;
        __syncthreads();

        int tn = t + GEMM_GB;
        if (tn < GMTILES) {                    // issue next-tile loads NOW
            sA0 = loadA(tn * 64 + r0, e0);
            sA1 = loadA(tn * 64 + r1, e1);
        }

        f32x4 acc[4][CB];
#pragma unroll
        for (int mi = 0; mi < 4; ++mi)
#pragma unroll
            for (int nf = 0; nf < CB; ++nf) acc[mi][nf] = f32x4{0.f, 0.f, 0.f, 0.f};

        const char* pA = reinterpret_cast<const char*>(As[cur]);
#pragma unroll
        for (int ks = 0; ks < 4; ++ks) {
            int k2 = (ks * 32 + lk) * 2;
            short8 a[4];
#pragma unroll
            for (int mi = 0; mi < 4; ++mi) {
                int r = mi * 16 + lr;
                int byte = (r * 256 + k2) ^ ((r & 7) << 4);
                a[mi] = *reinterpret_cast<const short8*>(pA + byte);
            }
#pragma unroll
            for (int mi = 0; mi < 4; ++mi)
#pragma unroll
                for (int nf = 0; nf < CB; ++nf)
                    acc[mi][nf] = __builtin_amdgcn_mfma_f32_16x16x32_bf16(
                        a[mi], bfr[ks][nf], acc[mi][nf], 0, 0, 0);
        }

        // epilogue: D col = lane&15, row = 4*(lane>>4) + reg
#pragma unroll
        for (int mi = 0; mi < 4; ++mi) {
#pragma unroll
            for (int nf = 0; nf < CB; ++nf) {
                int colg = wid * (16 * CB) + nf * 16 + lr;
#pragma unroll
                for (int rr = 0; rr < 4; ++rr) {
                    int rowg = t * 64 + mi * 16 + ((lane >> 4) << 2) + rr;
                    if (rowg < NN) {
                        float v = acc[mi][nf][rr];
                        if (colg < ZW) {
                            zb[(size_t)rowg * ZW + colg] = f2bf(v);
                        } else {
                            int c2 = colg - ZW;
                            if (YF32) ((float*)yout)[(size_t)rowg * ZW + c2]  = v + bias[c2];
                            else      ((ushort*)yout)[(size_t)rowg * ZW + c2] = f2bf(v + bias[c2]);
                        }
                    }
                }
            }
        }
        cur ^= 1;
    }
}

// ---------------------------------------------------------------------------
// Gather 1: hb[n] = relu( mean z1b[nbrs] + y1b[n] )  (128-wide bf16)
// Wave per node; halves take alternate edges; uint2 loads (8B).
// ---------------------------------------------------------------------------
__global__ __launch_bounds__(256) void k_gather1(const ushort* __restrict__ z1b,
                                                 const ushort* __restrict__ y1b,
                                                 const int* __restrict__ rowptr,
                                                 const int* __restrict__ rowend,
                                                 const int* __restrict__ col,
                                                 ushort* __restrict__ hb)
{
    const int w = threadIdx.x >> 6, lane = threadIdx.x & 63;
    const int n = blockIdx.x * 4 + w;
    if (n >= NN) return;
    const int half = lane >> 5, li = lane & 31;
    const int beg = rowptr[n], end = rowend[n];
    const uint2* zu = (const uint2*)z1b;      // row = 32 uint2
    float a0 = 0.f, a1 = 0.f, a2 = 0.f, a3 = 0.f;
    int e = beg;
    for (; e + 7 < end; e += 8) {
        int s0 = col[e     + half];
        int s1 = col[e + 2 + half];
        int s2 = col[e + 4 + half];
        int s3 = col[e + 6 + half];
        uint2 u0 = zu[(size_t)s0 * 32 + li];
        uint2 u1 = zu[(size_t)s1 * 32 + li];
        uint2 u2 = zu[(size_t)s2 * 32 + li];
        uint2 u3 = zu[(size_t)s3 * 32 + li];
        a0 += bflo(u0.x) + bflo(u1.x) + bflo(u2.x) + bflo(u3.x);
        a1 += bfhi(u0.x) + bfhi(u1.x) + bfhi(u2.x) + bfhi(u3.x);
        a2 += bflo(u0.y) + bflo(u1.y) + bflo(u2.y) + bflo(u3.y);
        a3 += bfhi(u0.y) + bfhi(u1.y) + bfhi(u2.y) + bfhi(u3.y);
    }
    for (; e + 1 < end; e += 2) {
        int s0 = col[e + half];
        uint2 u0 = zu[(size_t)s0 * 32 + li];
        a0 += bflo(u0.x); a1 += bfhi(u0.x);
        a2 += bflo(u0.y); a3 += bfhi(u0.y);
    }
    if (e < end && half == 0) {
        int s0 = col[e];
        uint2 u0 = zu[(size_t)s0 * 32 + li];
        a0 += bflo(u0.x); a1 += bfhi(u0.x);
        a2 += bflo(u0.y); a3 += bfhi(u0.y);
    }
    a0 += __shfl_xor(a0, 32); a1 += __shfl_xor(a1, 32);
    a2 += __shfl_xor(a2, 32); a3 += __shfl_xor(a3, 32);
    if (half == 0) {
        float inv = 1.0f / (float)max(end - beg, 1);
        uint2 uy = ((const uint2*)y1b)[(size_t)n * 32 + li];
        float h0 = fmaxf(a0 * inv + bflo(uy.x), 0.f);
        float h1 = fmaxf(a1 * inv + bfhi(uy.x), 0.f);
        float h2 = fmaxf(a2 * inv + bflo(uy.y), 0.f);
        float h3 = fmaxf(a3 * inv + bfhi(uy.y), 0.f);
        uint2 o;
        o.x = packbf(h0, h1);
        o.y = packbf(h2, h3);
        ((uint2*)hb)[(size_t)n * 32 + li] = o;
    }
}

// ---------------------------------------------------------------------------
// Gather 2: out[n] = mean z2b[nbrs] + y2f[n]  (64-wide, fp32 out)
// Wave per node; quarters take every 4th edge; uint2 loads.
// ---------------------------------------------------------------------------
__global__ __launch_bounds__(256) void k_gather2(const ushort* __restrict__ z2b,
                                                 const float* __restrict__ y2f,
                                                 const int* __restrict__ rowptr,
                                                 const int* __restrict__ rowend,
                                                 const int* __restrict__ col,
                                                 float* __restrict__ out)
{
    const int w = threadIdx.x >> 6, lane = threadIdx.x & 63;
    const int n = blockIdx.x * 4 + w;
    if (n >= NN) return;
    const int quar = lane >> 4, li = lane & 15;
    const int beg = rowptr[n], end = rowend[n];
    const uint2* zu = (const uint2*)z2b;      // row = 16 uint2
    float a0 = 0.f, a1 = 0.f, a2 = 0.f, a3 = 0.f;
    int e = beg;
    for (; e + 15 < end; e += 16) {
        int s0 = col[e      + quar];
        int s1 = col[e + 4  + quar];
        int s2 = col[e + 8  + quar];
        int s3 = col[e + 12 + quar];
        uint2 u0 = zu[(size_t)s0 * 16 + li];
        uint2 u1 = zu[(size_t)s1 * 16 + li];
        uint2 u2 = zu[(size_t)s2 * 16 + li];
        uint2 u3 = zu[(size_t)s3 * 16 + li];
        a0 += bflo(u0.x) + bflo(u1.x) + bflo(u2.x) + bflo(u3.x);
        a1 += bfhi(u0.x) + bfhi(u1.x) + bfhi(u2.x) + bfhi(u3.x);
        a2 += bflo(u0.y) + bflo(u1.y) + bflo(u2.y) + bflo(u3.y);
        a3 += bfhi(u0.y) + bfhi(u1.y) + bfhi(u2.y) + bfhi(u3.y);
    }
    for (; e + 3 < end; e += 4) {
        int s0 = col[e + quar];
        uint2 u0 = zu[(size_t)s0 * 16 + li];
        a0 += bflo(u0.x); a1 += bfhi(u0.x);
        a2 += bflo(u0.y); a3 += bfhi(u0.y);
    }
    int rem = end - e;
    if (quar < rem) {
        int s0 = col[e + quar];
        uint2 u0 = zu[(size_t)s0 * 16 + li];
        a0 += bflo(u0.x); a1 += bfhi(u0.x);
        a2 += bflo(u0.y); a3 += bfhi(u0.y);
    }
    a0 += __shfl_xor(a0, 16); a1 += __shfl_xor(a1, 16);
    a2 += __shfl_xor(a2, 16); a3 += __shfl_xor(a3, 16);
    a0 += __shfl_xor(a0, 32); a1 += __shfl_xor(a1, 32);
    a2 += __shfl_xor(a2, 32); a3 += __shfl_xor(a3, 32);
    if (quar == 0) {
        float inv = 1.0f / (float)max(end - beg, 1);
        float4 y = ((const float4*)y2f)[(size_t)n * 16 + li];
        float4 o;
        o.x = a0 * inv + y.x;
        o.y = a1 * inv + y.y;
        o.z = a2 * inv + y.z;
        o.w = a3 * inv + y.w;
        ((float4*)out)[(size_t)n * 16 + li] = o;
    }
}

extern "C" void kernel_launch(void* const* d_in, const int* in_sizes, int n_in,
                              void* d_out, int out_size, void* d_ws, size_t ws_size,
                              hipStream_t stream)
{
    const float* x   = (const float*)d_in[0];
    const int*   ei  = (const int*)d_in[1];
    const float* W1l = (const float*)d_in[2];
    const float* W1r = (const float*)d_in[3];
    const float* b1  = (const float*)d_in[4];
    const float* W2l = (const float*)d_in[5];
    const float* W2r = (const float*)d_in[6];
    const float* b2  = (const float*)d_in[7];
    float* out = (float*)d_out;

    const int* src = ei;
    const int* dst = ei + NE;

    // workspace layout
    int*  rowptr = (int*)d_ws;                      // NN
    int*  rowend = rowptr + NN;                     // NN
    int*  gcur   = rowend + NN;                     // 256
    uint* packed = (uint*)(gcur + 256);             // NP*BUCKET
    int*  colA   = (int*)(packed + (size_t)NP * BUCKET); // NP*BUCKET
    uintptr_t p = (uintptr_t)(colA + (size_t)NP * BUCKET);
    p = (p + 255) & ~(uintptr_t)255;
    ushort* WbT1 = (ushort*)p;  p += (size_t)256 * 128 * 2;
    ushort* WbT2 = (ushort*)p;  p += (size_t)128 * 128 * 2;
    p = (p + 255) & ~(uintptr_t)255;
    ushort* z1b = (ushort*)p;   p += (size_t)NN * 128 * 2;  // row-major bf16
    ushort* y1b = (ushort*)p;   p += (size_t)NN * 128 * 2;  // row-major bf16
    ushort* hb  = (ushort*)p;   p += (size_t)NN * 128 * 2;  // row-major bf16
    ushort* z2b = z1b;                              // [NN][64] bf16, alias
    float*  y2f = (float*)y1b;                      // [NN][64] fp32, alias

    // ---- prep (gcur init + weight cast) ----
    k_prep<<<1 + (256 * 128 + 128 * 128 + 255) / 256, 256, 0, stream>>>(
        W1l, W1r, W2l, W2r, WbT1, WbT2, gcur);

    // ---- CSR build (fixed buckets) ----
    k_binning<<<NBIN, 256, 0, stream>>>(src, dst, gcur, packed);
    k_pfill<<<NP, 256, 0, stream>>>(packed, gcur, rowptr, rowend, colA);

    // ---- layer 1 ----
    k_gemm<true, 2, false><<<GEMM_GB, 512, 0, stream>>>(x, WbT1, b1, z1b, y1b);
    k_gather1<<<(NN + 3) / 4, 256, 0, stream>>>(z1b, y1b, rowptr, rowend, colA, hb);

    // ---- layer 2 ----
    k_gemm<false, 1, true><<<GEMM_GB, 512, 0, stream>>>(hb, WbT2, b2, z2b, y2f);
    k_gather2<<<(NN + 3) / 4, 256, 0, stream>>>(z2b, y2f, rowptr, rowend, colA, out);
}